// Round 2
// baseline (241.719 us; speedup 1.0000x reference)
//
#include <hip/hip_runtime.h>
#include <math.h>

#define NEG_HUGE -1e30f
constexpr int B_ = 64, H_ = 128, C_ = 1024, Q_ = 128;

typedef __bf16 bf16x8 __attribute__((ext_vector_type(8)));
typedef float f32x4 __attribute__((ext_vector_type(4)));
typedef short short8 __attribute__((ext_vector_type(8)));
typedef short short4s __attribute__((ext_vector_type(4)));

__device__ __forceinline__ float bs2f(short s) {
  unsigned u = ((unsigned)(unsigned short)s) << 16;
  float f; __builtin_memcpy(&f, &u, 4); return f;
}
__device__ __forceinline__ short f2bs(float f) {
  unsigned u; __builtin_memcpy(&u, &f, 4);
  u = (u + 0x7fffu + ((u >> 16) & 1u)) >> 16;
  return (short)u;
}
__device__ __forceinline__ void nts4(float* p, float4 v) {
  f32x4 x; x[0] = v.x; x[1] = v.y; x[2] = v.z; x[3] = v.w;
  __builtin_nontemporal_store(x, (f32x4*)p);
}

// ---------------------------------------------------------------------------
// kq: qTw[b][q][h] = qin*cqw (bf16); qbf[b][h][q] = qin (bf16);
// s1m[b][q] = q.qw + qmask.  grid (2,B), block 256.
// ---------------------------------------------------------------------------
__global__ __launch_bounds__(256) void kq(const float* __restrict__ qin,
                                          const float* __restrict__ qw,
                                          const float* __restrict__ cqw,
                                          const float* __restrict__ qmask,
                                          short* __restrict__ qTw,
                                          short* __restrict__ qbf,
                                          float* __restrict__ s1m) {
  __shared__ float T[64 * 130];  // [q-local][h]
  const int t = threadIdx.x;
  const int q0 = blockIdx.x * 64, b = blockIdx.y;
#pragma unroll
  for (int p = 0; p < 8; ++p) {
    int fidx = t + 256 * p;
    int h = fidx >> 4, seg = fidx & 15;
    float4 v = *(const float4*)&qin[(b * H_ + h) * Q_ + q0 + seg * 4];
    T[(seg * 4 + 0) * 130 + h] = v.x;
    T[(seg * 4 + 1) * 130 + h] = v.y;
    T[(seg * 4 + 2) * 130 + h] = v.z;
    T[(seg * 4 + 3) * 130 + h] = v.w;
    short4s o; o[0] = f2bs(v.x); o[1] = f2bs(v.y); o[2] = f2bs(v.z); o[3] = f2bs(v.w);
    *(short4s*)&qbf[(b * H_ + h) * Q_ + q0 + seg * 4] = o;
  }
  __syncthreads();
  if (t < 64) {
    float acc = 0.f;
#pragma unroll 8
    for (int h = 0; h < 128; ++h) acc += T[t * 130 + h] * qw[h];
    float qm = (qmask[b * Q_ + q0 + t] > 0.f) ? 0.f : NEG_HUGE;
    s1m[b * Q_ + q0 + t] = acc + qm;
  }
  {
    const int q = t >> 2, off = t & 3;
    short* dst = qTw + (b * Q_ + q0 + q) * H_;
#pragma unroll
    for (int j = 0; j < 4; ++j) {
      int hbv = off * 32 + j * 8;
      short8 v;
#pragma unroll
      for (int i = 0; i < 8; ++i) v[i] = f2bs(T[q * 130 + hbv + i] * cqw[hbv + i]);
      *(short8*)&dst[hbv] = v;
    }
  }
}

// ---------------------------------------------------------------------------
// k1: self-transposing MFMA s2-tile (128c x 128q).  Reads c directly (kills
// kTc): coalesced dword loads build XOR-swizzled AL[c][h] in LDS; s0 computed
// inline in f32.  A/B fully LDS-resident -> K-loop has NO barriers.
// Fused row softmax -> a_att bf16; col partial stats + eP bf16 (transposed).
// grid (64 b, 8 cx) — b fastest so the 8 sharers of qTw[b] co-locate per XCD.
// ---------------------------------------------------------------------------
__global__ __launch_bounds__(256) void k1_mfma(
    const float* __restrict__ cin, const short* __restrict__ qTw,
    const float* __restrict__ s1m, const float* __restrict__ cmask,
    const float* __restrict__ ctxw,
    short* __restrict__ a_att, short* __restrict__ ePT,
    float* __restrict__ pcm, float* __restrict__ pcs) {
  __shared__ __align__(16) char uni[65536];
  short* AL = (short*)uni;            // [128 c][128 h] bf16, xor-swizzled
  short* BL = (short*)(uni + 32768);  // [128 q][128 h] bf16, xor-swizzled
  short* RP = (short*)uni;            // [128][136] bf16 (after K-loop)
  __shared__ float s1mL[128], scolL[128], pw[512], mpL[128], s0part[2][128];

  const int t = threadIdx.x;
  const int w = t >> 6, l = t & 63, quad = l >> 4, lcol = l & 15;
  const int b = blockIdx.x, bx = blockIdx.y, c0 = bx * 128;

  if (t < 128) s1mL[t] = s1m[b * Q_ + t];

  // ---- stage A: transpose c[b][h][c0+cl] -> AL[cl][h], s0 partial in f32 ----
  {
    const int cl = t & 127, hw = t >> 7;
    float s0c = 0.f;
#pragma unroll
    for (int it = 0; it < 8; ++it) {
      const int hb = hw + it * 2;  // h-block of 8
      const float* sp = cin + ((size_t)(b * H_ + hb * 8)) * C_ + c0 + cl;
      short8 o;
#pragma unroll
      for (int i = 0; i < 8; ++i) {
        float f = sp[(size_t)i * C_];
        o[i] = f2bs(f);
        s0c += f * ctxw[hb * 8 + i];
      }
      *(short8*)&AL[cl * 128 + 8 * (hb ^ (cl & 7))] = o;
    }
    s0part[hw][cl] = s0c;
  }
  // ---- stage B: qTw[b][q][h] -> BL (xor-swizzled short8 copy) ----
  {
    const int q = t >> 1, hb0 = (t & 1) * 8;
#pragma unroll
    for (int i = 0; i < 8; ++i) {
      const int hb = hb0 + i;
      *(short8*)&BL[q * 128 + 8 * (hb ^ (q & 7))] =
          *(const short8*)&qTw[(b * Q_ + q) * H_ + hb * 8];
    }
  }
  __syncthreads();  // AL/BL/s0part ready
  if (t < 128) {
    float cm = (cmask[b * C_ + c0 + t] > 0.f) ? 0.f : NEG_HUGE;
    scolL[t] = cm + s0part[0][t] + s0part[1][t];
  }

  f32x4 acc[2][8];
#pragma unroll
  for (int mt = 0; mt < 2; ++mt)
#pragma unroll
    for (int nt = 0; nt < 8; ++nt) acc[mt][nt] = (f32x4){0.f, 0.f, 0.f, 0.f};

  // ---- K-loop: no barriers (operands fully resident) ----
#pragma unroll
  for (int kc = 0; kc < 4; ++kc) {
    const int kb = kc * 4 + quad;
    const int sw = 8 * (kb ^ (lcol & 7));
    bf16x8 af0 = *(bf16x8*)&AL[(w * 32 + lcol) * 128 + sw];
    bf16x8 af1 = *(bf16x8*)&AL[(w * 32 + 16 + lcol) * 128 + sw];
#pragma unroll
    for (int nt = 0; nt < 8; ++nt) {
      bf16x8 bfrag = *(bf16x8*)&BL[(nt * 16 + lcol) * 128 + sw];
      acc[0][nt] = __builtin_amdgcn_mfma_f32_16x16x32_bf16(af0, bfrag, acc[0][nt], 0, 0, 0);
      acc[1][nt] = __builtin_amdgcn_mfma_f32_16x16x32_bf16(af1, bfrag, acc[1][nt], 0, 0, 0);
    }
  }
  __syncthreads();  // orders scolL; frees AL/BL for RP reuse

  float s1v[8];
#pragma unroll
  for (int nt = 0; nt < 8; ++nt) s1v[nt] = s1mL[nt * 16 + lcol];
  float cs0[2][4];
#pragma unroll
  for (int mt = 0; mt < 2; ++mt)
#pragma unroll
    for (int r = 0; r < 4; ++r)
      cs0[mt][r] = scolL[w * 32 + mt * 16 + quad * 4 + r];

  // ---- row max ----
  float rm[2][4];
#pragma unroll
  for (int mt = 0; mt < 2; ++mt)
#pragma unroll
    for (int r = 0; r < 4; ++r) {
      float m = -INFINITY;
#pragma unroll
      for (int nt = 0; nt < 8; ++nt) m = fmaxf(m, acc[mt][nt][r] + s1v[nt]);
      rm[mt][r] = m;
    }
#pragma unroll
  for (int d = 1; d <= 8; d <<= 1)
#pragma unroll
    for (int mt = 0; mt < 2; ++mt)
#pragma unroll
      for (int r = 0; r < 4; ++r)
        rm[mt][r] = fmaxf(rm[mt][r], __shfl_xor(rm[mt][r], d));

  // ---- col partial max from RAW logits ----
  float pmv[8];
#pragma unroll
  for (int nt = 0; nt < 8; ++nt) {
    float m = -INFINITY;
#pragma unroll
    for (int mt = 0; mt < 2; ++mt)
#pragma unroll
      for (int r = 0; r < 4; ++r) m = fmaxf(m, acc[mt][nt][r] + cs0[mt][r]);
    pmv[nt] = m;
  }
#pragma unroll
  for (int nt = 0; nt < 8; ++nt) {
    pmv[nt] = fmaxf(pmv[nt], __shfl_xor(pmv[nt], 16));
    pmv[nt] = fmaxf(pmv[nt], __shfl_xor(pmv[nt], 32));
  }
  if (l < 16) {
#pragma unroll
    for (int nt = 0; nt < 8; ++nt) pw[w * 128 + nt * 16 + lcol] = pmv[nt];
  }

  // ---- overwrite acc with row-exp (once) ----
#pragma unroll
  for (int mt = 0; mt < 2; ++mt)
#pragma unroll
    for (int nt = 0; nt < 8; ++nt)
#pragma unroll
      for (int r = 0; r < 4; ++r)
        acc[mt][nt][r] = __expf(acc[mt][nt][r] + s1v[nt] - rm[mt][r]);

  // ---- row sums -> inverse ----
  float inv[2][4];
#pragma unroll
  for (int mt = 0; mt < 2; ++mt)
#pragma unroll
    for (int r = 0; r < 4; ++r) {
      float s = 0.f;
#pragma unroll
      for (int nt = 0; nt < 8; ++nt) s += acc[mt][nt][r];
      inv[mt][r] = s;
    }
#pragma unroll
  for (int d = 1; d <= 8; d <<= 1)
#pragma unroll
    for (int mt = 0; mt < 2; ++mt)
#pragma unroll
      for (int r = 0; r < 4; ++r)
        inv[mt][r] += __shfl_xor(inv[mt][r], d);
#pragma unroll
  for (int mt = 0; mt < 2; ++mt)
#pragma unroll
    for (int r = 0; r < 4; ++r) inv[mt][r] = 1.f / inv[mt][r];

  // repack normalized a_att -> RP[c][q]
#pragma unroll
  for (int mt = 0; mt < 2; ++mt)
#pragma unroll
    for (int nt = 0; nt < 8; ++nt)
#pragma unroll
      for (int r = 0; r < 4; ++r) {
        int row = w * 32 + mt * 16 + quad * 4 + r;
        int col = nt * 16 + lcol;
        RP[row * 136 + col] = f2bs(acc[mt][nt][r] * inv[mt][r]);
      }
  __syncthreads();  // (B)
  {
    const int row = t >> 1, half = t & 1;
    short* dst = a_att + (b * C_ + c0 + row) * Q_ + half * 64;
    const short* srcp = RP + row * 136 + half * 64;
#pragma unroll
    for (int j = 0; j < 8; ++j) *(short8*)&dst[j * 8] = *(const short8*)&srcp[j * 8];
  }
  __syncthreads();  // (C)
  if (t < 128) {
    float m = fmaxf(fmaxf(pw[t], pw[128 + t]), fmaxf(pw[256 + t], pw[384 + t]));
    mpL[t] = m;
    pcm[(b * 8 + bx) * Q_ + t] = m;
  }
  __syncthreads();  // (D)
  float mpv[8];
#pragma unroll
  for (int nt = 0; nt < 8; ++nt) mpv[nt] = mpL[nt * 16 + lcol];

  // ---- col sums + eP repack; colval = rowexp * exp(crm - sm) ----
  float crm[2][4];
#pragma unroll
  for (int mt = 0; mt < 2; ++mt)
#pragma unroll
    for (int r = 0; r < 4; ++r) crm[mt][r] = cs0[mt][r] + rm[mt][r];
  float psv[8];
#pragma unroll
  for (int nt = 0; nt < 8; ++nt) {
    const float sm = s1v[nt] + mpv[nt];
    const int qq = nt * 16 + lcol;
    float s = 0.f;
#pragma unroll
    for (int mt = 0; mt < 2; ++mt)
#pragma unroll
      for (int r = 0; r < 4; ++r) {
        float v = acc[mt][nt][r] * __expf(crm[mt][r] - sm);
        s += v;
        RP[qq * 136 + (w * 32 + mt * 16 + quad * 4 + r)] = f2bs(v);
      }
    psv[nt] = s;
  }
#pragma unroll
  for (int nt = 0; nt < 8; ++nt) {
    psv[nt] += __shfl_xor(psv[nt], 16);
    psv[nt] += __shfl_xor(psv[nt], 32);
  }
  if (l < 16) {
#pragma unroll
    for (int nt = 0; nt < 8; ++nt) pw[w * 128 + nt * 16 + lcol] = psv[nt];
  }
  __syncthreads();  // (E)
  if (t < 128) pcs[(b * 8 + bx) * Q_ + t] = pw[t] + pw[128 + t] + pw[256 + t] + pw[384 + t];
  {
    const int qq = t >> 1, half = t & 1;
    short* dst = ePT + (b * Q_ + qq) * C_ + c0 + half * 64;
    const short* srcp = RP + qq * 136 + half * 64;
#pragma unroll
    for (int j = 0; j < 8; ++j) *(short8*)&dst[j * 8] = *(const short8*)&srcp[j * 8];
  }
}

// ---------------------------------------------------------------------------
// k3: full-K.  TmT[b][h][q] = icL[q]*sum_{all c} scale*eP[q][c]*c[h][c].
// Kills Tpart round-trip + k3b dispatch.  Per-block output 16h x 128q.
// grid (64 b, 8 hs) — b fastest: 8 sharers of ePT[b] co-locate per XCD.
// ---------------------------------------------------------------------------
__global__ __launch_bounds__(256) void k3_T(
    const short* __restrict__ ePT, const float* __restrict__ cin,
    const float* __restrict__ pcm, const float* __restrict__ pcs,
    short* __restrict__ TmT) {
  __shared__ __align__(16) char uni[36864];
  short* AL = (short*)uni;            // [128 q][128 c] bf16, xor-swizzled
  short* BL = (short*)(uni + 32768);  // [16 h][128 c] bf16, xor-swizzled
  float* RPF = (float*)uni;           // [16][136] f32 (after loop)
  __shared__ float scT[8][128];       // per-c-tile softmax rescale, per q
  __shared__ float icL[128];          // 1/colsum per q
  const int t = threadIdx.x;
  const int w = t >> 6, l = t & 63, quad = l >> 4, lcol = l & 15;
  const int b = blockIdx.x, hs = blockIdx.y;

  if (t < 128) {  // in-block combine of 8 column partials (L2-hot, tiny)
    float m[8]; float M = -INFINITY;
#pragma unroll
    for (int k = 0; k < 8; ++k) { m[k] = pcm[(b * 8 + k) * Q_ + t]; M = fmaxf(M, m[k]); }
    float s = 0.f;
#pragma unroll
    for (int k = 0; k < 8; ++k) {
      float e = __expf(m[k] - M);
      scT[k][t] = e;
      s += pcs[(b * 8 + k) * Q_ + t] * e;
    }
    icL[t] = 1.f / s;
  }

  f32x4 acc[2];
  acc[0] = (f32x4){0.f, 0.f, 0.f, 0.f};
  acc[1] = (f32x4){0.f, 0.f, 0.f, 0.f};

  const int q = t >> 1, cb0 = (t & 1) * 8;   // A-stage mapping
  const int h = t >> 4, co2 = (t & 15) * 8;  // B-stage mapping
  __syncthreads();  // scT/icL ready

  for (int ck = 0; ck < 8; ++ck) {  // K-chunks of 128 c (= one c-tile each)
    const float sA = scT[ck][q];
#pragma unroll
    for (int i = 0; i < 8; ++i) {
      const int cb = cb0 + i;
      short8 v = *(const short8*)&ePT[(b * Q_ + q) * C_ + ck * 128 + cb * 8];
      short8 o;
#pragma unroll
      for (int j = 0; j < 8; ++j) o[j] = f2bs(bs2f(v[j]) * sA);
      *(short8*)&AL[q * 128 + 8 * (cb ^ (q & 7))] = o;
    }
    {
      const float* sp = cin + ((size_t)(b * H_ + hs * 16 + h)) * C_ + ck * 128 + co2;
      float4 v0 = *(const float4*)&sp[0];
      float4 v1 = *(const float4*)&sp[4];
      short8 o;
      o[0] = f2bs(v0.x); o[1] = f2bs(v0.y); o[2] = f2bs(v0.z); o[3] = f2bs(v0.w);
      o[4] = f2bs(v1.x); o[5] = f2bs(v1.y); o[6] = f2bs(v1.z); o[7] = f2bs(v1.w);
      *(short8*)&BL[h * 128 + 8 * ((co2 >> 3) ^ (h & 7))] = o;
    }
    __syncthreads();
#pragma unroll
    for (int ks = 0; ks < 4; ++ks) {
      const int kb = ks * 4 + quad;
      const int sw = 8 * (kb ^ (lcol & 7));
      bf16x8 bfrag = *(bf16x8*)&BL[lcol * 128 + sw];
      bf16x8 af0 = *(bf16x8*)&AL[(w * 32 + lcol) * 128 + sw];
      bf16x8 af1 = *(bf16x8*)&AL[(w * 32 + 16 + lcol) * 128 + sw];
      acc[0] = __builtin_amdgcn_mfma_f32_16x16x32_bf16(af0, bfrag, acc[0], 0, 0, 0);
      acc[1] = __builtin_amdgcn_mfma_f32_16x16x32_bf16(af1, bfrag, acc[1], 0, 0, 0);
    }
    __syncthreads();
  }
  // RPF[h-local][q]  (D col = B-row = h, D row = A-row = q)
#pragma unroll
  for (int mt = 0; mt < 2; ++mt)
#pragma unroll
    for (int r = 0; r < 4; ++r)
      RPF[lcol * 136 + (w * 32 + mt * 16 + quad * 4 + r)] = acc[mt][r];
  __syncthreads();
  {
    const int hh = t >> 4, qo = (t & 15) * 8;
    short8 o;
#pragma unroll
    for (int i = 0; i < 8; ++i) o[i] = f2bs(RPF[hh * 136 + qo + i] * icL[qo + i]);
    *(short8*)&TmT[(b * H_ + hs * 16 + hh) * Q_ + qo] = o;
  }
}

// ---------------------------------------------------------------------------
// k4: a = a_att@qT, b = a_att@Tm (MFMA); emit [c, a, c*a, c*b].
// grid (64 b, 2 hy, 8 cx) — b fastest: cx-sharers of qbf/TmT and hy-sharers
// of a_att co-locate per XCD.  Non-temporal coalesced stores.
// ---------------------------------------------------------------------------
__global__ __launch_bounds__(256) void k4_out(
    const short* __restrict__ a_att, const short* __restrict__ qbf,
    const short* __restrict__ TmT, const float* __restrict__ cin,
    float* __restrict__ out) {
  __shared__ __align__(16) char uni[34816];
  short* AL = (short*)uni;             // [128][40]
  short* B1 = (short*)(uni + 10240);   // [64][40]
  short* B2 = (short*)(uni + 15360);   // [64][40]
  float* RPF = (float*)uni;            // [64][136] f32
  const int t = threadIdx.x;
  const int w = t >> 6, l = t & 63, quad = l >> 4, lcol = l & 15;
  const int b = blockIdx.x, hb = blockIdx.y * 64, c0 = blockIdx.z * 128;

  f32x4 accA[2][4], accB[2][4];
#pragma unroll
  for (int mt = 0; mt < 2; ++mt)
#pragma unroll
    for (int nt = 0; nt < 4; ++nt) {
      accA[mt][nt] = (f32x4){0.f, 0.f, 0.f, 0.f};
      accB[mt][nt] = (f32x4){0.f, 0.f, 0.f, 0.f};
    }

  const int ar = t >> 2, aoff = t & 3;
  for (int kc = 0; kc < 4; ++kc) {
    const int q0 = kc * 32;
    *(short8*)&AL[ar * 40 + aoff * 8] =
        *(const short8*)&a_att[(b * C_ + c0 + ar) * Q_ + q0 + aoff * 8];
    *(short8*)&AL[(64 + ar) * 40 + aoff * 8] =
        *(const short8*)&a_att[(b * C_ + c0 + 64 + ar) * Q_ + q0 + aoff * 8];
    *(short8*)&B1[ar * 40 + aoff * 8] =
        *(const short8*)&qbf[(b * H_ + hb + ar) * Q_ + q0 + aoff * 8];
    *(short8*)&B2[ar * 40 + aoff * 8] =
        *(const short8*)&TmT[(b * H_ + hb + ar) * Q_ + q0 + aoff * 8];
    __syncthreads();
    bf16x8 af0 = *(bf16x8*)&AL[(w * 32 + lcol) * 40 + quad * 8];
    bf16x8 af1 = *(bf16x8*)&AL[(w * 32 + 16 + lcol) * 40 + quad * 8];
#pragma unroll
    for (int nt = 0; nt < 4; ++nt) {
      bf16x8 bq = *(bf16x8*)&B1[(nt * 16 + lcol) * 40 + quad * 8];
      bf16x8 bt = *(bf16x8*)&B2[(nt * 16 + lcol) * 40 + quad * 8];
      accA[0][nt] = __builtin_amdgcn_mfma_f32_16x16x32_bf16(af0, bq, accA[0][nt], 0, 0, 0);
      accA[1][nt] = __builtin_amdgcn_mfma_f32_16x16x32_bf16(af1, bq, accA[1][nt], 0, 0, 0);
      accB[0][nt] = __builtin_amdgcn_mfma_f32_16x16x32_bf16(af0, bt, accB[0][nt], 0, 0, 0);
      accB[1][nt] = __builtin_amdgcn_mfma_f32_16x16x32_bf16(af1, bt, accB[1][nt], 0, 0, 0);
    }
    __syncthreads();
  }

  const int lr = t >> 5, coln = (t & 31) * 4;
  float* ob = out + (size_t)b * 512 * 1024;
  float4 cvv[8];

  // pass A: slabs c, a, c*a
#pragma unroll
  for (int mt = 0; mt < 2; ++mt)
#pragma unroll
    for (int nt = 0; nt < 4; ++nt)
#pragma unroll
      for (int r = 0; r < 4; ++r)
        RPF[(nt * 16 + lcol) * 136 + (w * 32 + mt * 16 + quad * 4 + r)] = accA[mt][nt][r];
  __syncthreads();
#pragma unroll
  for (int iter = 0; iter < 8; ++iter) {
    int hl = iter * 8 + lr;
    int hrow = hb + hl;
    float4 la = *(float4*)&RPF[hl * 136 + coln];
    float4 cv = *(const float4*)&cin[(b * H_ + hrow) * C_ + c0 + coln];
    cvv[iter] = cv;
    nts4(&ob[(size_t)hrow * 1024 + c0 + coln], cv);
    nts4(&ob[(size_t)(128 + hrow) * 1024 + c0 + coln], la);
    float4 p = make_float4(cv.x * la.x, cv.y * la.y, cv.z * la.z, cv.w * la.w);
    nts4(&ob[(size_t)(256 + hrow) * 1024 + c0 + coln], p);
  }
  __syncthreads();
  // pass B: slab c*b
#pragma unroll
  for (int mt = 0; mt < 2; ++mt)
#pragma unroll
    for (int nt = 0; nt < 4; ++nt)
#pragma unroll
      for (int r = 0; r < 4; ++r)
        RPF[(nt * 16 + lcol) * 136 + (w * 32 + mt * 16 + quad * 4 + r)] = accB[mt][nt][r];
  __syncthreads();
#pragma unroll
  for (int iter = 0; iter < 8; ++iter) {
    int hl = iter * 8 + lr;
    int hrow = hb + hl;
    float4 lb = *(float4*)&RPF[hl * 136 + coln];
    float4 cv = cvv[iter];
    float4 p = make_float4(cv.x * lb.x, cv.y * lb.y, cv.z * lb.z, cv.w * lb.w);
    nts4(&ob[(size_t)(384 + hrow) * 1024 + c0 + coln], p);
  }
}

// ---------------------------------------------------------------------------
extern "C" void kernel_launch(void* const* d_in, const int* in_sizes, int n_in,
                              void* d_out, int out_size, void* d_ws, size_t ws_size,
                              hipStream_t stream) {
  const float* c     = (const float*)d_in[0];
  const float* q     = (const float*)d_in[1];
  const float* cmask = (const float*)d_in[2];
  const float* qmask = (const float*)d_in[3];
  const float* ctxw  = (const float*)d_in[4];
  const float* qw    = (const float*)d_in[5];
  const float* cqw   = (const float*)d_in[6];
  float* out = (float*)d_out;

  char* ws = (char*)d_ws;
  short* qTw    = (short*)(ws);                       //  2,097,152 B
  short* qbf    = (short*)(ws + 2097152);             //  2,097,152 B
  short* a_att  = (short*)(ws + 4194304);             // 16,777,216 B
  short* ePT    = (short*)(ws + 20971520);            // 16,777,216 B
  short* TmT    = (short*)(ws + 37748736);            //  2,097,152 B
  float* s1m    = (float*)(ws + 39845888);            //     32,768 B
  float* pcm    = (float*)(ws + 39878656);            //    262,144 B
  float* pcs    = (float*)(ws + 40140800);            //    262,144 B

  kq<<<dim3(2, B_), dim3(256), 0, stream>>>(q, qw, cqw, qmask, qTw, qbf, s1m);
  k1_mfma<<<dim3(B_, 8), dim3(256), 0, stream>>>(c, qTw, s1m, cmask, ctxw,
                                                 a_att, ePT, pcm, pcs);
  k3_T<<<dim3(B_, 8), dim3(256), 0, stream>>>(ePT, c, pcm, pcs, TmT);
  k4_out<<<dim3(B_, 2, 8), dim3(256), 0, stream>>>(a_att, qbf, TmT, c, out);
}

// Round 3
// 226.425 us; speedup vs baseline: 1.0675x; 1.0675x over previous
//
#include <hip/hip_runtime.h>
#include <math.h>

#define NEG_HUGE -1e30f
constexpr int B_ = 64, H_ = 128, C_ = 1024, Q_ = 128;

typedef __bf16 bf16x8 __attribute__((ext_vector_type(8)));
typedef float f32x4 __attribute__((ext_vector_type(4)));
typedef short short8 __attribute__((ext_vector_type(8)));
typedef short short4s __attribute__((ext_vector_type(4)));

__device__ __forceinline__ float bs2f(short s) {
  unsigned u = ((unsigned)(unsigned short)s) << 16;
  float f; __builtin_memcpy(&f, &u, 4); return f;
}
__device__ __forceinline__ short f2bs(float f) {
  unsigned u; __builtin_memcpy(&u, &f, 4);
  u = (u + 0x7fffu + ((u >> 16) & 1u)) >> 16;
  return (short)u;
}
__device__ __forceinline__ void nts4(float* p, float4 v) {
  f32x4 x; x[0] = v.x; x[1] = v.y; x[2] = v.z; x[3] = v.w;
  __builtin_nontemporal_store(x, (f32x4*)p);
}

// ---------------------------------------------------------------------------
// kq: qTw[b][q][h] = qin*cqw (bf16); qbf[b][h][q] = qin (bf16);
// s1m[b][q] = q.qw + qmask.  grid (2,B), block 256.
// ---------------------------------------------------------------------------
__global__ __launch_bounds__(256) void kq(const float* __restrict__ qin,
                                          const float* __restrict__ qw,
                                          const float* __restrict__ cqw,
                                          const float* __restrict__ qmask,
                                          short* __restrict__ qTw,
                                          short* __restrict__ qbf,
                                          float* __restrict__ s1m) {
  __shared__ float T[64 * 130];  // [q-local][h]
  const int t = threadIdx.x;
  const int q0 = blockIdx.x * 64, b = blockIdx.y;
#pragma unroll
  for (int p = 0; p < 8; ++p) {
    int fidx = t + 256 * p;
    int h = fidx >> 4, seg = fidx & 15;
    float4 v = *(const float4*)&qin[(b * H_ + h) * Q_ + q0 + seg * 4];
    T[(seg * 4 + 0) * 130 + h] = v.x;
    T[(seg * 4 + 1) * 130 + h] = v.y;
    T[(seg * 4 + 2) * 130 + h] = v.z;
    T[(seg * 4 + 3) * 130 + h] = v.w;
    short4s o; o[0] = f2bs(v.x); o[1] = f2bs(v.y); o[2] = f2bs(v.z); o[3] = f2bs(v.w);
    *(short4s*)&qbf[(b * H_ + h) * Q_ + q0 + seg * 4] = o;
  }
  __syncthreads();
  if (t < 64) {
    float acc = 0.f;
#pragma unroll 8
    for (int h = 0; h < 128; ++h) acc += T[t * 130 + h] * qw[h];
    float qm = (qmask[b * Q_ + q0 + t] > 0.f) ? 0.f : NEG_HUGE;
    s1m[b * Q_ + q0 + t] = acc + qm;
  }
  {
    const int q = t >> 2, off = t & 3;
    short* dst = qTw + (b * Q_ + q0 + q) * H_;
#pragma unroll
    for (int j = 0; j < 4; ++j) {
      int hbv = off * 32 + j * 8;
      short8 v;
#pragma unroll
      for (int i = 0; i < 8; ++i) v[i] = f2bs(T[q * 130 + hbv + i] * cqw[hbv + i]);
      *(short8*)&dst[hbv] = v;
    }
  }
}

// ---------------------------------------------------------------------------
// k1: self-transposing MFMA s2-tile (128c x 128q).  Reads c directly:
// coalesced dword loads build XOR-swizzled AL[c][h]; s0 computed inline in
// f32; ALSO emits cbf[b][h][c] bf16 (same f2bs rounding) for k3's B operand.
// Fused row softmax -> a_att bf16; col partial stats + eP bf16 (transposed).
// grid (64 b, 8 cx) — b fastest so the 8 sharers of qTw[b] co-locate per XCD.
// ---------------------------------------------------------------------------
__global__ __launch_bounds__(256) void k1_mfma(
    const float* __restrict__ cin, const short* __restrict__ qTw,
    const float* __restrict__ s1m, const float* __restrict__ cmask,
    const float* __restrict__ ctxw,
    short* __restrict__ a_att, short* __restrict__ ePT,
    short* __restrict__ cbf,
    float* __restrict__ pcm, float* __restrict__ pcs) {
  __shared__ __align__(16) char uni[65536];
  short* AL = (short*)uni;            // [128 c][128 h] bf16, xor-swizzled
  short* BL = (short*)(uni + 32768);  // [128 q][128 h] bf16, xor-swizzled
  short* RP = (short*)uni;            // [128][136] bf16 (after K-loop)
  __shared__ float s1mL[128], scolL[128], pw[512], mpL[128], s0part[2][128];

  const int t = threadIdx.x;
  const int w = t >> 6, l = t & 63, quad = l >> 4, lcol = l & 15;
  const int b = blockIdx.x, bx = blockIdx.y, c0 = bx * 128;

  if (t < 128) s1mL[t] = s1m[b * Q_ + t];

  // ---- stage A: transpose c[b][h][c0+cl] -> AL[cl][h]; s0 partial f32;
  //      cbf coalesced 2B stores (write-only, fire-and-forget) ----
  {
    const int cl = t & 127, hw = t >> 7;
    float s0c = 0.f;
#pragma unroll
    for (int it = 0; it < 8; ++it) {
      const int hb = hw + it * 2;  // h-block of 8
      const float* sp = cin + ((size_t)(b * H_ + hb * 8)) * C_ + c0 + cl;
      short* cb = cbf + ((size_t)(b * H_ + hb * 8)) * C_ + c0 + cl;
      short8 o;
#pragma unroll
      for (int i = 0; i < 8; ++i) {
        float f = sp[(size_t)i * C_];
        o[i] = f2bs(f);
        s0c += f * ctxw[hb * 8 + i];
        cb[(size_t)i * C_] = o[i];
      }
      *(short8*)&AL[cl * 128 + 8 * (hb ^ (cl & 7))] = o;
    }
    s0part[hw][cl] = s0c;
  }
  // ---- stage B: qTw[b][q][h] -> BL (xor-swizzled short8 copy) ----
  {
    const int q = t >> 1, hb0 = (t & 1) * 8;
#pragma unroll
    for (int i = 0; i < 8; ++i) {
      const int hb = hb0 + i;
      *(short8*)&BL[q * 128 + 8 * (hb ^ (q & 7))] =
          *(const short8*)&qTw[(b * Q_ + q) * H_ + hb * 8];
    }
  }
  __syncthreads();  // AL/BL/s0part ready
  if (t < 128) {
    float cm = (cmask[b * C_ + c0 + t] > 0.f) ? 0.f : NEG_HUGE;
    scolL[t] = cm + s0part[0][t] + s0part[1][t];
  }

  f32x4 acc[2][8];
#pragma unroll
  for (int mt = 0; mt < 2; ++mt)
#pragma unroll
    for (int nt = 0; nt < 8; ++nt) acc[mt][nt] = (f32x4){0.f, 0.f, 0.f, 0.f};

  // ---- K-loop: no barriers (operands fully resident) ----
#pragma unroll
  for (int kc = 0; kc < 4; ++kc) {
    const int kb = kc * 4 + quad;
    const int sw = 8 * (kb ^ (lcol & 7));
    bf16x8 af0 = *(bf16x8*)&AL[(w * 32 + lcol) * 128 + sw];
    bf16x8 af1 = *(bf16x8*)&AL[(w * 32 + 16 + lcol) * 128 + sw];
#pragma unroll
    for (int nt = 0; nt < 8; ++nt) {
      bf16x8 bfrag = *(bf16x8*)&BL[(nt * 16 + lcol) * 128 + sw];
      acc[0][nt] = __builtin_amdgcn_mfma_f32_16x16x32_bf16(af0, bfrag, acc[0][nt], 0, 0, 0);
      acc[1][nt] = __builtin_amdgcn_mfma_f32_16x16x32_bf16(af1, bfrag, acc[1][nt], 0, 0, 0);
    }
  }
  __syncthreads();  // orders scolL; frees AL/BL for RP reuse

  float s1v[8];
#pragma unroll
  for (int nt = 0; nt < 8; ++nt) s1v[nt] = s1mL[nt * 16 + lcol];
  float cs0[2][4];
#pragma unroll
  for (int mt = 0; mt < 2; ++mt)
#pragma unroll
    for (int r = 0; r < 4; ++r)
      cs0[mt][r] = scolL[w * 32 + mt * 16 + quad * 4 + r];

  // ---- row max ----
  float rm[2][4];
#pragma unroll
  for (int mt = 0; mt < 2; ++mt)
#pragma unroll
    for (int r = 0; r < 4; ++r) {
      float m = -INFINITY;
#pragma unroll
      for (int nt = 0; nt < 8; ++nt) m = fmaxf(m, acc[mt][nt][r] + s1v[nt]);
      rm[mt][r] = m;
    }
#pragma unroll
  for (int d = 1; d <= 8; d <<= 1)
#pragma unroll
    for (int mt = 0; mt < 2; ++mt)
#pragma unroll
      for (int r = 0; r < 4; ++r)
        rm[mt][r] = fmaxf(rm[mt][r], __shfl_xor(rm[mt][r], d));

  // ---- col partial max from RAW logits ----
  float pmv[8];
#pragma unroll
  for (int nt = 0; nt < 8; ++nt) {
    float m = -INFINITY;
#pragma unroll
    for (int mt = 0; mt < 2; ++mt)
#pragma unroll
      for (int r = 0; r < 4; ++r) m = fmaxf(m, acc[mt][nt][r] + cs0[mt][r]);
    pmv[nt] = m;
  }
#pragma unroll
  for (int nt = 0; nt < 8; ++nt) {
    pmv[nt] = fmaxf(pmv[nt], __shfl_xor(pmv[nt], 16));
    pmv[nt] = fmaxf(pmv[nt], __shfl_xor(pmv[nt], 32));
  }
  if (l < 16) {
#pragma unroll
    for (int nt = 0; nt < 8; ++nt) pw[w * 128 + nt * 16 + lcol] = pmv[nt];
  }

  // ---- overwrite acc with row-exp (once) ----
#pragma unroll
  for (int mt = 0; mt < 2; ++mt)
#pragma unroll
    for (int nt = 0; nt < 8; ++nt)
#pragma unroll
      for (int r = 0; r < 4; ++r)
        acc[mt][nt][r] = __expf(acc[mt][nt][r] + s1v[nt] - rm[mt][r]);

  // ---- row sums -> inverse ----
  float inv[2][4];
#pragma unroll
  for (int mt = 0; mt < 2; ++mt)
#pragma unroll
    for (int r = 0; r < 4; ++r) {
      float s = 0.f;
#pragma unroll
      for (int nt = 0; nt < 8; ++nt) s += acc[mt][nt][r];
      inv[mt][r] = s;
    }
#pragma unroll
  for (int d = 1; d <= 8; d <<= 1)
#pragma unroll
    for (int mt = 0; mt < 2; ++mt)
#pragma unroll
      for (int r = 0; r < 4; ++r)
        inv[mt][r] += __shfl_xor(inv[mt][r], d);
#pragma unroll
  for (int mt = 0; mt < 2; ++mt)
#pragma unroll
    for (int r = 0; r < 4; ++r) inv[mt][r] = 1.f / inv[mt][r];

  // repack normalized a_att -> RP[c][q]
#pragma unroll
  for (int mt = 0; mt < 2; ++mt)
#pragma unroll
    for (int nt = 0; nt < 8; ++nt)
#pragma unroll
      for (int r = 0; r < 4; ++r) {
        int row = w * 32 + mt * 16 + quad * 4 + r;
        int col = nt * 16 + lcol;
        RP[row * 136 + col] = f2bs(acc[mt][nt][r] * inv[mt][r]);
      }
  __syncthreads();  // (B)
  {
    const int row = t >> 1, half = t & 1;
    short* dst = a_att + (b * C_ + c0 + row) * Q_ + half * 64;
    const short* srcp = RP + row * 136 + half * 64;
#pragma unroll
    for (int j = 0; j < 8; ++j) *(short8*)&dst[j * 8] = *(const short8*)&srcp[j * 8];
  }
  __syncthreads();  // (C)
  if (t < 128) {
    float m = fmaxf(fmaxf(pw[t], pw[128 + t]), fmaxf(pw[256 + t], pw[384 + t]));
    mpL[t] = m;
    pcm[(b * 8 + bx) * Q_ + t] = m;
  }
  __syncthreads();  // (D)
  float mpv[8];
#pragma unroll
  for (int nt = 0; nt < 8; ++nt) mpv[nt] = mpL[nt * 16 + lcol];

  // ---- col sums + eP repack; colval = rowexp * exp(crm - sm) ----
  float crm[2][4];
#pragma unroll
  for (int mt = 0; mt < 2; ++mt)
#pragma unroll
    for (int r = 0; r < 4; ++r) crm[mt][r] = cs0[mt][r] + rm[mt][r];
  float psv[8];
#pragma unroll
  for (int nt = 0; nt < 8; ++nt) {
    const float sm = s1v[nt] + mpv[nt];
    const int qq = nt * 16 + lcol;
    float s = 0.f;
#pragma unroll
    for (int mt = 0; mt < 2; ++mt)
#pragma unroll
      for (int r = 0; r < 4; ++r) {
        float v = acc[mt][nt][r] * __expf(crm[mt][r] - sm);
        s += v;
        RP[qq * 136 + (w * 32 + mt * 16 + quad * 4 + r)] = f2bs(v);
      }
    psv[nt] = s;
  }
#pragma unroll
  for (int nt = 0; nt < 8; ++nt) {
    psv[nt] += __shfl_xor(psv[nt], 16);
    psv[nt] += __shfl_xor(psv[nt], 32);
  }
  if (l < 16) {
#pragma unroll
    for (int nt = 0; nt < 8; ++nt) pw[w * 128 + nt * 16 + lcol] = psv[nt];
  }
  __syncthreads();  // (E)
  if (t < 128) pcs[(b * 8 + bx) * Q_ + t] = pw[t] + pw[128 + t] + pw[256 + t] + pw[384 + t];
  {
    const int qq = t >> 1, half = t & 1;
    short* dst = ePT + (b * Q_ + qq) * C_ + c0 + half * 64;
    const short* srcp = RP + qq * 136 + half * 64;
#pragma unroll
    for (int j = 0; j < 8; ++j) *(short8*)&dst[j * 8] = *(const short8*)&srcp[j * 8];
  }
}

// ---------------------------------------------------------------------------
// k3: q-split full-K.  TmT[b][h][qslice] = icL[q]*sum_c scale*eP[q][c]*cbf[h][c].
// q-split -> ZERO ePT re-read (disjoint row strips); shared operand is the
// tiny cbf[b] (256 KB, L2-resident for the 8 co-located sharers).  B-staging
// is pure short8 copies (no f32 cvt).  grid (64 b, 8 qs) — b fastest.
// ---------------------------------------------------------------------------
__global__ __launch_bounds__(256) void k3_T(
    const short* __restrict__ ePT, const short* __restrict__ cbf,
    const float* __restrict__ pcm, const float* __restrict__ pcs,
    short* __restrict__ TmT) {
  __shared__ __align__(16) char uni[36864];
  short* AL = (short*)uni;            // [16 q][128 c] bf16, xor-swizzled
  short* BL = (short*)(uni + 4096);   // [128 h][128 c] bf16, xor-swizzled
  short* RP = (short*)uni;            // [128 h][16 q] bf16 (epilogue, = AL area)
  __shared__ float scT[8][128];       // per-c-tile softmax rescale, per q
  __shared__ float icL[128];          // 1/colsum per q
  const int t = threadIdx.x;
  const int w = t >> 6, l = t & 63, quad = l >> 4, lcol = l & 15;
  const int b = blockIdx.x, qg = blockIdx.y * 16;

  if (t < 128) {  // in-block combine of 8 column partials (L2-hot, tiny)
    float m[8]; float M = -INFINITY;
#pragma unroll
    for (int k = 0; k < 8; ++k) { m[k] = pcm[(b * 8 + k) * Q_ + t]; M = fmaxf(M, m[k]); }
    float s = 0.f;
#pragma unroll
    for (int k = 0; k < 8; ++k) {
      float e = __expf(m[k] - M);
      scT[k][t] = e;
      s += pcs[(b * 8 + k) * Q_ + t] * e;
    }
    icL[t] = 1.f / s;
  }

  f32x4 acc[2];
  acc[0] = (f32x4){0.f, 0.f, 0.f, 0.f};
  acc[1] = (f32x4){0.f, 0.f, 0.f, 0.f};

  const int qa = t >> 4, cs = t & 15;  // A-stage: 16 q rows x 16 slots
  const int hh = t >> 4;               // B-stage: 16 h rows/pass, same cs
  __syncthreads();  // scT/icL ready

  for (int ck = 0; ck < 8; ++ck) {  // K-chunks of 128 c (= one c-tile each)
    // A: scaled ePT strip (disjoint per block)
    {
      const float sA = scT[ck][qg + qa];
      short8 v = *(const short8*)&ePT[(b * Q_ + qg + qa) * C_ + ck * 128 + cs * 8];
      short8 o;
#pragma unroll
      for (int j = 0; j < 8; ++j) o[j] = f2bs(bs2f(v[j]) * sA);
      *(short8*)&AL[qa * 128 + 8 * (cs ^ (qa & 7))] = o;
    }
    // B: cbf[b][h][c-chunk] straight short8 copies
#pragma unroll
    for (int p = 0; p < 8; ++p) {
      const int h = p * 16 + hh;
      *(short8*)&BL[h * 128 + 8 * (cs ^ (h & 7))] =
          *(const short8*)&cbf[(b * H_ + h) * C_ + ck * 128 + cs * 8];
    }
    __syncthreads();
#pragma unroll
    for (int ks = 0; ks < 4; ++ks) {
      const int kb = ks * 4 + quad;
      bf16x8 af = *(bf16x8*)&AL[lcol * 128 + 8 * (kb ^ (lcol & 7))];
#pragma unroll
      for (int nt = 0; nt < 2; ++nt) {
        const int hr = w * 32 + nt * 16 + lcol;
        bf16x8 bfrag = *(bf16x8*)&BL[hr * 128 + 8 * (kb ^ (hr & 7))];
        acc[nt] = __builtin_amdgcn_mfma_f32_16x16x32_bf16(af, bfrag, acc[nt], 0, 0, 0);
      }
    }
    __syncthreads();
  }
  // acc[nt][r]: q = qg + quad*4 + r, h = w*32 + nt*16 + lcol
#pragma unroll
  for (int nt = 0; nt < 2; ++nt)
#pragma unroll
    for (int r = 0; r < 4; ++r) {
      const int qi = quad * 4 + r;
      RP[(w * 32 + nt * 16 + lcol) * 16 + qi] = f2bs(acc[nt][r] * icL[qg + qi]);
    }
  __syncthreads();
  {
    const int h = t >> 1, half = t & 1;
    *(short8*)&TmT[(b * H_ + h) * Q_ + qg + half * 8] =
        *(const short8*)&RP[h * 16 + half * 8];
  }
}

// ---------------------------------------------------------------------------
// k4: a = a_att@qT, b = a_att@Tm (MFMA); emit [c, a, c*a, c*b].
// grid (64 b, 2 hy, 8 cx) — b fastest.  Non-temporal coalesced stores.
// ---------------------------------------------------------------------------
__global__ __launch_bounds__(256) void k4_out(
    const short* __restrict__ a_att, const short* __restrict__ qbf,
    const short* __restrict__ TmT, const float* __restrict__ cin,
    float* __restrict__ out) {
  __shared__ __align__(16) char uni[34816];
  short* AL = (short*)uni;             // [128][40]
  short* B1 = (short*)(uni + 10240);   // [64][40]
  short* B2 = (short*)(uni + 15360);   // [64][40]
  float* RPF = (float*)uni;            // [64][136] f32
  const int t = threadIdx.x;
  const int w = t >> 6, l = t & 63, quad = l >> 4, lcol = l & 15;
  const int b = blockIdx.x, hb = blockIdx.y * 64, c0 = blockIdx.z * 128;

  f32x4 accA[2][4], accB[2][4];
#pragma unroll
  for (int mt = 0; mt < 2; ++mt)
#pragma unroll
    for (int nt = 0; nt < 4; ++nt) {
      accA[mt][nt] = (f32x4){0.f, 0.f, 0.f, 0.f};
      accB[mt][nt] = (f32x4){0.f, 0.f, 0.f, 0.f};
    }

  const int ar = t >> 2, aoff = t & 3;
  for (int kc = 0; kc < 4; ++kc) {
    const int q0 = kc * 32;
    *(short8*)&AL[ar * 40 + aoff * 8] =
        *(const short8*)&a_att[(b * C_ + c0 + ar) * Q_ + q0 + aoff * 8];
    *(short8*)&AL[(64 + ar) * 40 + aoff * 8] =
        *(const short8*)&a_att[(b * C_ + c0 + 64 + ar) * Q_ + q0 + aoff * 8];
    *(short8*)&B1[ar * 40 + aoff * 8] =
        *(const short8*)&qbf[(b * H_ + hb + ar) * Q_ + q0 + aoff * 8];
    *(short8*)&B2[ar * 40 + aoff * 8] =
        *(const short8*)&TmT[(b * H_ + hb + ar) * Q_ + q0 + aoff * 8];
    __syncthreads();
    bf16x8 af0 = *(bf16x8*)&AL[(w * 32 + lcol) * 40 + quad * 8];
    bf16x8 af1 = *(bf16x8*)&AL[(w * 32 + 16 + lcol) * 40 + quad * 8];
#pragma unroll
    for (int nt = 0; nt < 4; ++nt) {
      bf16x8 bq = *(bf16x8*)&B1[(nt * 16 + lcol) * 40 + quad * 8];
      bf16x8 bt = *(bf16x8*)&B2[(nt * 16 + lcol) * 40 + quad * 8];
      accA[0][nt] = __builtin_amdgcn_mfma_f32_16x16x32_bf16(af0, bq, accA[0][nt], 0, 0, 0);
      accA[1][nt] = __builtin_amdgcn_mfma_f32_16x16x32_bf16(af1, bq, accA[1][nt], 0, 0, 0);
      accB[0][nt] = __builtin_amdgcn_mfma_f32_16x16x32_bf16(af0, bt, accB[0][nt], 0, 0, 0);
      accB[1][nt] = __builtin_amdgcn_mfma_f32_16x16x32_bf16(af1, bt, accB[1][nt], 0, 0, 0);
    }
    __syncthreads();
  }

  const int lr = t >> 5, coln = (t & 31) * 4;
  float* ob = out + (size_t)b * 512 * 1024;
  float4 cvv[8];

  // pass A: slabs c, a, c*a
#pragma unroll
  for (int mt = 0; mt < 2; ++mt)
#pragma unroll
    for (int nt = 0; nt < 4; ++nt)
#pragma unroll
      for (int r = 0; r < 4; ++r)
        RPF[(nt * 16 + lcol) * 136 + (w * 32 + mt * 16 + quad * 4 + r)] = accA[mt][nt][r];
  __syncthreads();
#pragma unroll
  for (int iter = 0; iter < 8; ++iter) {
    int hl = iter * 8 + lr;
    int hrow = hb + hl;
    float4 la = *(float4*)&RPF[hl * 136 + coln];
    float4 cv = *(const float4*)&cin[(b * H_ + hrow) * C_ + c0 + coln];
    cvv[iter] = cv;
    nts4(&ob[(size_t)hrow * 1024 + c0 + coln], cv);
    nts4(&ob[(size_t)(128 + hrow) * 1024 + c0 + coln], la);
    float4 p = make_float4(cv.x * la.x, cv.y * la.y, cv.z * la.z, cv.w * la.w);
    nts4(&ob[(size_t)(256 + hrow) * 1024 + c0 + coln], p);
  }
  __syncthreads();
  // pass B: slab c*b
#pragma unroll
  for (int mt = 0; mt < 2; ++mt)
#pragma unroll
    for (int nt = 0; nt < 4; ++nt)
#pragma unroll
      for (int r = 0; r < 4; ++r)
        RPF[(nt * 16 + lcol) * 136 + (w * 32 + mt * 16 + quad * 4 + r)] = accB[mt][nt][r];
  __syncthreads();
#pragma unroll
  for (int iter = 0; iter < 8; ++iter) {
    int hl = iter * 8 + lr;
    int hrow = hb + hl;
    float4 lb = *(float4*)&RPF[hl * 136 + coln];
    float4 cv = cvv[iter];
    float4 p = make_float4(cv.x * lb.x, cv.y * lb.y, cv.z * lb.z, cv.w * lb.w);
    nts4(&ob[(size_t)(384 + hrow) * 1024 + c0 + coln], p);
  }
}

// ---------------------------------------------------------------------------
extern "C" void kernel_launch(void* const* d_in, const int* in_sizes, int n_in,
                              void* d_out, int out_size, void* d_ws, size_t ws_size,
                              hipStream_t stream) {
  const float* c     = (const float*)d_in[0];
  const float* q     = (const float*)d_in[1];
  const float* cmask = (const float*)d_in[2];
  const float* qmask = (const float*)d_in[3];
  const float* ctxw  = (const float*)d_in[4];
  const float* qw    = (const float*)d_in[5];
  const float* cqw   = (const float*)d_in[6];
  float* out = (float*)d_out;

  char* ws = (char*)d_ws;
  short* qTw    = (short*)(ws);                       //  2,097,152 B
  short* qbf    = (short*)(ws + 2097152);             //  2,097,152 B
  short* a_att  = (short*)(ws + 4194304);             // 16,777,216 B
  short* ePT    = (short*)(ws + 20971520);            // 16,777,216 B
  short* cbf    = (short*)(ws + 37748736);            // 16,777,216 B
  short* TmT    = (short*)(ws + 54525952);            //  2,097,152 B
  float* s1m    = (float*)(ws + 56623104);            //     32,768 B
  float* pcm    = (float*)(ws + 56655872);            //    262,144 B
  float* pcs    = (float*)(ws + 56918016);            //    262,144 B

  kq<<<dim3(2, B_), dim3(256), 0, stream>>>(q, qw, cqw, qmask, qTw, qbf, s1m);
  k1_mfma<<<dim3(B_, 8), dim3(256), 0, stream>>>(c, qTw, s1m, cmask, ctxw,
                                                 a_att, ePT, cbf, pcm, pcs);
  k3_T<<<dim3(B_, 8), dim3(256), 0, stream>>>(ePT, cbf, pcm, pcs, TmT);
  k4_out<<<dim3(B_, 2, 8), dim3(256), 0, stream>>>(a_att, qbf, TmT, c, out);
}